// Round 5
// baseline (351.329 us; speedup 1.0000x reference)
//
#include <hip/hip_runtime.h>
#include <hip/hip_bf16.h>

typedef __attribute__((ext_vector_type(8))) short bf16x8;
typedef __attribute__((ext_vector_type(4))) float f32x4;
typedef __attribute__((ext_vector_type(4))) unsigned int u32x4;
typedef __attribute__((ext_vector_type(4))) unsigned short u16x4;

// ---------------- bf16 helpers ----------------
__device__ __forceinline__ unsigned short f2bf(float f) {
  __hip_bfloat16 h = __float2bfloat16(f);
  return __builtin_bit_cast(unsigned short, h);
}
__device__ __forceinline__ float bfw(unsigned int word, int hi) {
  union { unsigned int i; float f; } v;
  v.i = hi ? (word & 0xffff0000u) : (word << 16);
  return v.f;
}

// ---------------- init: Wigner 3j coefficients + weight transpose ----------------
struct cplx { double re, im; };
__device__ __forceinline__ cplx cmul(cplx a, cplx b) {
  return {a.re * b.re - a.im * b.im, a.re * b.im + a.im * b.re};
}
__device__ __forceinline__ double fct_(int n) {
  const double f[8] = {1., 1., 2., 6., 24., 120., 720., 5040.};
  return f[n];
}
__device__ __forceinline__ int imax_(int a, int b) { return a > b ? a : b; }
__device__ __forceinline__ int imin_(int a, int b) { return a < b ? a : b; }

__device__ double su2_cg(int j1, int j2, int j3, int m1, int m2, int m3) {
  if (m3 != m1 + m2) return 0.0;
  int vmin = imax_(imax_(-j1 + j2 + m3, -j1 + m1), 0);
  int vmax = imin_(imin_(j2 + j3 + m1, j3 - j1 + j2), j3 + m3);
  double C = sqrt((2.0 * j3 + 1.0) * fct_(j3 + j1 - j2) * fct_(j3 - j1 + j2) * fct_(j1 + j2 - j3)
                  * fct_(j3 + m3) * fct_(j3 - m3)
                  / (fct_(j1 + j2 + j3 + 1) * fct_(j1 - m1) * fct_(j1 + m1) * fct_(j2 - m2) * fct_(j2 + m2)));
  double S = 0.0;
  for (int v = vmin; v <= vmax; ++v) {
    double sgn = ((v + j2 + m2) & 1) ? -1.0 : 1.0;
    S += sgn * fct_(j2 + j3 + m1 - v) * fct_(j1 - m1 + v)
         / (fct_(v) * fct_(j3 - j1 + j2 - v) * fct_(j3 + m3 - v) * fct_(v + j1 - j2 - m3));
  }
  return C * S;
}

__device__ cplx q_entry(int l, int r, int c) {
  const double s2 = 0.70710678118654752440;
  int m = r - l;
  cplx v = {0.0, 0.0};
  if (m < 0) {
    if (c == l - m) v = {s2, 0.0};          // col l+|m|
    else if (c == l + m) v = {0.0, -s2};    // col l-|m|
  } else if (m == 0) {
    if (c == l) v = {1.0, 0.0};
  } else {
    double sgn = (m & 1) ? -1.0 : 1.0;
    if (c == l + m) v = {sgn * s2, 0.0};
    else if (c == l - m) v = {0.0, sgn * s2};
  }
  cplx f;
  switch (l & 3) {
    case 0: f = {1.0, 0.0}; break;
    case 1: f = {0.0, -1.0}; break;
    case 2: f = {-1.0, 0.0}; break;
    default: f = {0.0, 1.0}; break;
  }
  return cmul(f, v);
}

// blocks 0..703: transpose weights fp32 [p][u][w] -> bf16 [p][w][u]
// blocks 704..714: Wigner 3j * path-normalization into cgw[p*125 + i*25 + j*5 + k]
__global__ void init_kernel(const float* __restrict__ w, unsigned short* __restrict__ Wt,
                            float* __restrict__ cgw) {
  const int blk = blockIdx.x;
  const int tid = threadIdx.x;
  if (blk < 704) {
    int g = blk * 256 + tid;                 // 704*256 == 180224 exactly
    int p = g >> 14, rem = g & 16383;
    int u = rem >> 7, wc = rem & 127;
    Wt[(p << 14) + (wc << 7) + u] = f2bf(w[g]);
    return;
  }
  const int p = blk - 704;
  const int L1t[11] = {0,0,0,1,1,1,1,2,2,2,2};
  const int L2t[11] = {0,1,2,0,1,1,2,0,1,2,2};
  const int L3t[11] = {0,1,2,1,0,2,1,2,1,0,2};
  const double FAN[11] = {384.,512.,512.,512.,384.,512.,512.,512.,512.,384.,512.};
  const int l1 = L1t[p], l2 = L2t[p], l3 = L3t[p];
  const int n1 = 2 * l1 + 1, n2 = 2 * l2 + 1, n3 = 2 * l3 + 1;
  if (tid >= n1 * n2 * n3) return;
  const int a = tid / (n2 * n3), b = (tid / n3) % n2, c = tid % n3;
  double sre = 0.0;
  for (int i = 0; i < n1; ++i)
    for (int k = 0; k < n2; ++k)
      for (int n = 0; n < n3; ++n) {
        double cg = su2_cg(l1, l2, l3, i - l1, k - l2, n - l3);
        if (cg == 0.0) continue;
        cplx q1 = q_entry(l1, i, a);
        cplx q2 = q_entry(l2, k, b);
        cplx q3 = q_entry(l3, n, c);
        q3.im = -q3.im;                      // conj(Q3)
        cplx pr = cmul(cmul(q1, q2), q3);
        sre += pr.re * cg;
      }
  // wigner3j = Re(R)/sqrt(2l3+1); path weight = sqrt((2l3+1)/fan)  =>  Re(R)/sqrt(fan)
  cgw[p * 125 + a * 25 + b * 5 + c] = (float)(sre / sqrt(FAN[p]));
}

// ---------------- main kernel ----------------
// LDS x1 tile layout (bf16, shorts): group l1=0 at 0 (pitch 136), l1=1 at 4352
// (pitch 392), l1=2 at 16896 (pitch 648). Total 37632 shorts = 75264 B.
__device__ __forceinline__ void stage_all(const float* __restrict__ x1, int Mbase,
                                          unsigned short* __restrict__ s_a) {
  const int tid = threadIdx.x;
#pragma unroll
  for (int rep = 0; rep < 36; ++rep) {
    int it = tid + rep * 256;                // 9216 float4-loads total
    int row = it / 288, c4 = it % 288;
    int col = c4 << 2;
    const f32x4 v = __builtin_nontemporal_load(
        (const f32x4*)&x1[(size_t)(Mbase + row) * 1152 + col]);
    u16x4 h;
    h.x = f2bf(v.x); h.y = f2bf(v.y); h.z = f2bf(v.z); h.w = f2bf(v.w);
    int dst;
    if (col < 128)      dst = row * 136 + col;
    else if (col < 512) dst = 4352 + row * 392 + (col - 128);
    else                dst = 16896 + row * 648 + (col - 512);
    *(u16x4*)&s_a[dst] = h;
  }
}

template<int PID, int L1, int L2, int L3>
__device__ __forceinline__ void do_path(const float* __restrict__ s_cgw,
                                        const unsigned short* __restrict__ s_a,
                                        const unsigned short* __restrict__ Wt,
                                        const float (&x2v)[9],
                                        int bloc, int kg, int r16, int nbase,
                                        f32x4 (&acc)[2 * L3 + 1][4]) {
  constexpr int D1 = 2 * L1 + 1, D2 = 2 * L2 + 1, D3 = 2 * L3 + 1;
  constexpr int O2 = (L2 == 0) ? 0 : ((L2 == 1) ? 1 : 4);
  constexpr int GB = (L1 == 0) ? 0 : ((L1 == 1) ? 4352 : 16896);
  constexpr int pitch = 128 * D1 + 8;
  // g[i][k] = sum_j x2[o2+j] * cgw[i][j][k]  (per-lane, for this lane's batch row)
  float g[D1][D3];
#pragma unroll
  for (int i = 0; i < D1; ++i)
#pragma unroll
    for (int k = 0; k < D3; ++k) {
      float s = 0.f;
#pragma unroll
      for (int j = 0; j < D2; ++j)
        s += x2v[O2 + j] * s_cgw[PID * 125 + i * 25 + j * 5 + k];
      g[i][k] = s;
    }
  const unsigned short* __restrict__ wbase = Wt + (PID << 14);
  const unsigned short* __restrict__ ap0 = s_a + GB + bloc * pitch;
#pragma unroll
  for (int us = 0; us < 4; ++us) {
    const int u0 = us * 32 + kg * 8;
    // x1 octet: 8 consecutive u, D1 comps each, bf16, from LDS
    const unsigned short* ap = ap0 + u0 * D1;
    u32x4 av[D1];
#pragma unroll
    for (int d = 0; d < D1; ++d) av[d] = *(const u32x4*)(ap + d * 8);
    // weight frags: 8 consecutive u for this lane's w column
    u32x4 bw[4];
#pragma unroll
    for (int nf = 0; nf < 4; ++nf)
      bw[nf] = *(const u32x4*)&wbase[(nbase + nf * 16 + r16) * 128 + u0];
    // t frags (A operand), one per output component k
    unsigned int taw[D3][4];
#pragma unroll
    for (int jp = 0; jp < 4; ++jp) {
      float a0[D1], a1[D1];
#pragma unroll
      for (int i = 0; i < D1; ++i) {
        int e0 = (2 * jp) * D1 + i, e1 = e0 + D1;
        a0[i] = bfw(av[e0 >> 3][(e0 & 7) >> 1], e0 & 1);
        a1[i] = bfw(av[e1 >> 3][(e1 & 7) >> 1], e1 & 1);
      }
#pragma unroll
      for (int k = 0; k < D3; ++k) {
        float t0 = 0.f, t1 = 0.f;
#pragma unroll
        for (int i = 0; i < D1; ++i) { t0 += a0[i] * g[i][k]; t1 += a1[i] * g[i][k]; }
        taw[k][jp] = (unsigned int)f2bf(t0) | ((unsigned int)f2bf(t1) << 16);
      }
    }
#pragma unroll
    for (int k = 0; k < D3; ++k) {
      u32x4 tw;
      tw.x = taw[k][0]; tw.y = taw[k][1]; tw.z = taw[k][2]; tw.w = taw[k][3];
      bf16x8 ta = __builtin_bit_cast(bf16x8, tw);
#pragma unroll
      for (int nf = 0; nf < 4; ++nf)
        acc[k][nf] = __builtin_amdgcn_mfma_f32_16x16x32_bf16(
            ta, __builtin_bit_cast(bf16x8, bw[nf]), acc[k][nf], 0, 0, 0);
    }
  }
}

// amdgpu_waves_per_eu(2,2): LDS (80896B) already caps us at 2 blocks/CU = 2
// waves/SIMD, so force the register allocator to the full 256-VGPR budget
// instead of its 128-reg/4-wave heuristic target (which spilled ~600B/thread,
// the 313MB WRITE_SIZE excess seen in R4).
__global__ __attribute__((amdgpu_waves_per_eu(2, 2))) void __launch_bounds__(256)
fctp_main(
    const float* __restrict__ x1, const float* __restrict__ x2,
    const float* __restrict__ cgw, const unsigned short* __restrict__ Wt,
    float* __restrict__ out) {
  __shared__ float s_cgw[1375];
  __shared__ __align__(16) unsigned short s_a[37632];   // 75264 B x1 tile (bf16)
  const int tid = threadIdx.x;
  const int Mbase = blockIdx.x << 5;

  for (int i = tid; i < 1375; i += 256) s_cgw[i] = cgw[i];
  stage_all(x1, Mbase, s_a);

  const int lane = tid & 63, wid = tid >> 6;
  const int mi = wid >> 1, ni = wid & 1;
  const int r16 = lane & 15, kg = lane >> 4;
  const int bloc = (mi << 4) + r16;   // this lane's batch row within the tile (A side)
  const int nbase = ni << 6;          // this wave's w window

  float x2v[9];
  const float* __restrict__ x2p = x2 + (size_t)(Mbase + bloc) * 9;
#pragma unroll
  for (int j = 0; j < 9; ++j) x2v[j] = x2p[j];

  __syncthreads();                    // the only barrier: x1 tile + cgw ready

  const int bout = Mbase + (mi << 4) + (kg << 2);

  // ---- i3 = 0 (cols [0,128), d3=1): paths 0,4,9 ----
  {
    f32x4 acc[1][4] = {};
    do_path<0, 0, 0, 0>(s_cgw, s_a, Wt, x2v, bloc, kg, r16, nbase, acc);
    do_path<4, 1, 1, 0>(s_cgw, s_a, Wt, x2v, bloc, kg, r16, nbase, acc);
    do_path<9, 2, 2, 0>(s_cgw, s_a, Wt, x2v, bloc, kg, r16, nbase, acc);
#pragma unroll
    for (int nf = 0; nf < 4; ++nf) {
      const int w = nbase + nf * 16 + r16;
#pragma unroll
      for (int r = 0; r < 4; ++r)
        __builtin_nontemporal_store(acc[0][nf][r],
                                    &out[(size_t)(bout + r) * 1152 + w]);
    }
  }
  // ---- i3 = 1 (cols 128 + w*3 + k, d3=3): paths 1,3,6,8 ----
  {
    f32x4 acc[3][4] = {};
    do_path<1, 0, 1, 1>(s_cgw, s_a, Wt, x2v, bloc, kg, r16, nbase, acc);
    do_path<3, 1, 0, 1>(s_cgw, s_a, Wt, x2v, bloc, kg, r16, nbase, acc);
    do_path<6, 1, 2, 1>(s_cgw, s_a, Wt, x2v, bloc, kg, r16, nbase, acc);
    do_path<8, 2, 1, 1>(s_cgw, s_a, Wt, x2v, bloc, kg, r16, nbase, acc);
#pragma unroll
    for (int nf = 0; nf < 4; ++nf) {
      const int w = nbase + nf * 16 + r16;
#pragma unroll
      for (int r = 0; r < 4; ++r) {
        float* o = out + (size_t)(bout + r) * 1152 + 128 + w * 3;
#pragma unroll
        for (int k = 0; k < 3; ++k) o[k] = acc[k][nf][r];
      }
    }
  }
  // ---- i3 = 2 (cols 512 + w*5 + k, d3=5): paths 2,5,7,10 ----
  {
    f32x4 acc[5][4] = {};
    do_path<2, 0, 2, 2>(s_cgw, s_a, Wt, x2v, bloc, kg, r16, nbase, acc);
    do_path<5, 1, 1, 2>(s_cgw, s_a, Wt, x2v, bloc, kg, r16, nbase, acc);
    do_path<7, 2, 0, 2>(s_cgw, s_a, Wt, x2v, bloc, kg, r16, nbase, acc);
    do_path<10, 2, 2, 2>(s_cgw, s_a, Wt, x2v, bloc, kg, r16, nbase, acc);
#pragma unroll
    for (int nf = 0; nf < 4; ++nf) {
      const int w = nbase + nf * 16 + r16;
#pragma unroll
      for (int r = 0; r < 4; ++r) {
        float* o = out + (size_t)(bout + r) * 1152 + 512 + w * 5;
#pragma unroll
        for (int k = 0; k < 5; ++k) o[k] = acc[k][nf][r];
      }
    }
  }
}

extern "C" void kernel_launch(void* const* d_in, const int* in_sizes, int n_in,
                              void* d_out, int out_size, void* d_ws, size_t ws_size,
                              hipStream_t stream) {
  (void)in_sizes; (void)n_in; (void)out_size; (void)ws_size;
  const float* x1 = (const float*)d_in[0];
  const float* x2 = (const float*)d_in[1];
  const float* w  = (const float*)d_in[2];
  float* out = (float*)d_out;
  float* cgw = (float*)d_ws;                                    // 1375 floats
  unsigned short* Wt = (unsigned short*)((char*)d_ws + 8192);   // 11*128*128 bf16
  init_kernel<<<dim3(715), dim3(256), 0, stream>>>(w, Wt, cgw);
  fctp_main<<<dim3(2048), dim3(256), 0, stream>>>(x1, x2, cgw, Wt, out);
}

// Round 6
// 277.153 us; speedup vs baseline: 1.2676x; 1.2676x over previous
//
#include <hip/hip_runtime.h>
#include <hip/hip_bf16.h>

typedef __attribute__((ext_vector_type(8))) short bf16x8;
typedef __attribute__((ext_vector_type(4))) float f32x4;
typedef __attribute__((ext_vector_type(4))) unsigned int u32x4;
typedef __attribute__((ext_vector_type(4))) unsigned short u16x4;

// ---------------- bf16 helpers ----------------
__device__ __forceinline__ unsigned short f2bf(float f) {
  __hip_bfloat16 h = __float2bfloat16(f);
  return __builtin_bit_cast(unsigned short, h);
}
__device__ __forceinline__ float bfw(unsigned int word, int hi) {
  union { unsigned int i; float f; } v;
  v.i = hi ? (word & 0xffff0000u) : (word << 16);
  return v.f;
}

// ---------------- init: Wigner 3j coefficients + weight transpose ----------------
struct cplx { double re, im; };
__device__ __forceinline__ cplx cmul(cplx a, cplx b) {
  return {a.re * b.re - a.im * b.im, a.re * b.im + a.im * b.re};
}
__device__ __forceinline__ double fct_(int n) {
  const double f[8] = {1., 1., 2., 6., 24., 120., 720., 5040.};
  return f[n];
}
__device__ __forceinline__ int imax_(int a, int b) { return a > b ? a : b; }
__device__ __forceinline__ int imin_(int a, int b) { return a < b ? a : b; }

__device__ double su2_cg(int j1, int j2, int j3, int m1, int m2, int m3) {
  if (m3 != m1 + m2) return 0.0;
  int vmin = imax_(imax_(-j1 + j2 + m3, -j1 + m1), 0);
  int vmax = imin_(imin_(j2 + j3 + m1, j3 - j1 + j2), j3 + m3);
  double C = sqrt((2.0 * j3 + 1.0) * fct_(j3 + j1 - j2) * fct_(j3 - j1 + j2) * fct_(j1 + j2 - j3)
                  * fct_(j3 + m3) * fct_(j3 - m3)
                  / (fct_(j1 + j2 + j3 + 1) * fct_(j1 - m1) * fct_(j1 + m1) * fct_(j2 - m2) * fct_(j2 + m2)));
  double S = 0.0;
  for (int v = vmin; v <= vmax; ++v) {
    double sgn = ((v + j2 + m2) & 1) ? -1.0 : 1.0;
    S += sgn * fct_(j2 + j3 + m1 - v) * fct_(j1 - m1 + v)
         / (fct_(v) * fct_(j3 - j1 + j2 - v) * fct_(j3 + m3 - v) * fct_(v + j1 - j2 - m3));
  }
  return C * S;
}

__device__ cplx q_entry(int l, int r, int c) {
  const double s2 = 0.70710678118654752440;
  int m = r - l;
  cplx v = {0.0, 0.0};
  if (m < 0) {
    if (c == l - m) v = {s2, 0.0};          // col l+|m|
    else if (c == l + m) v = {0.0, -s2};    // col l-|m|
  } else if (m == 0) {
    if (c == l) v = {1.0, 0.0};
  } else {
    double sgn = (m & 1) ? -1.0 : 1.0;
    if (c == l + m) v = {sgn * s2, 0.0};
    else if (c == l - m) v = {0.0, sgn * s2};
  }
  cplx f;
  switch (l & 3) {
    case 0: f = {1.0, 0.0}; break;
    case 1: f = {0.0, -1.0}; break;
    case 2: f = {-1.0, 0.0}; break;
    default: f = {0.0, 1.0}; break;
  }
  return cmul(f, v);
}

// blocks 0..703: transpose weights fp32 [p][u][w] -> bf16 [p][w][u]
// blocks 704..714: Wigner 3j * path-normalization into cgw[p*125 + i*25 + j*5 + k]
__global__ void init_kernel(const float* __restrict__ w, unsigned short* __restrict__ Wt,
                            float* __restrict__ cgw) {
  const int blk = blockIdx.x;
  const int tid = threadIdx.x;
  if (blk < 704) {
    int g = blk * 256 + tid;                 // 704*256 == 180224 exactly
    int p = g >> 14, rem = g & 16383;
    int u = rem >> 7, wc = rem & 127;
    Wt[(p << 14) + (wc << 7) + u] = f2bf(w[g]);
    return;
  }
  const int p = blk - 704;
  const int L1t[11] = {0,0,0,1,1,1,1,2,2,2,2};
  const int L2t[11] = {0,1,2,0,1,1,2,0,1,2,2};
  const int L3t[11] = {0,1,2,1,0,2,1,2,1,0,2};
  const double FAN[11] = {384.,512.,512.,512.,384.,512.,512.,512.,512.,384.,512.};
  const int l1 = L1t[p], l2 = L2t[p], l3 = L3t[p];
  const int n1 = 2 * l1 + 1, n2 = 2 * l2 + 1, n3 = 2 * l3 + 1;
  if (tid >= n1 * n2 * n3) return;
  const int a = tid / (n2 * n3), b = (tid / n3) % n2, c = tid % n3;
  double sre = 0.0;
  for (int i = 0; i < n1; ++i)
    for (int k = 0; k < n2; ++k)
      for (int n = 0; n < n3; ++n) {
        double cg = su2_cg(l1, l2, l3, i - l1, k - l2, n - l3);
        if (cg == 0.0) continue;
        cplx q1 = q_entry(l1, i, a);
        cplx q2 = q_entry(l2, k, b);
        cplx q3 = q_entry(l3, n, c);
        q3.im = -q3.im;                      // conj(Q3)
        cplx pr = cmul(cmul(q1, q2), q3);
        sre += pr.re * cg;
      }
  // wigner3j = Re(R)/sqrt(2l3+1); path weight = sqrt((2l3+1)/fan)  =>  Re(R)/sqrt(fan)
  cgw[p * 125 + a * 25 + b * 5 + c] = (float)(sre / sqrt(FAN[p]));
}

// ---------------- main kernel ----------------
// LDS x1 tile layout (bf16, shorts): group l1=0 at 0 (pitch 136), l1=1 at 4352
// (pitch 392), l1=2 at 16896 (pitch 648). Total 37632 shorts = 75264 B.
__device__ __forceinline__ void stage_all(const float* __restrict__ x1, int Mbase,
                                          unsigned short* __restrict__ s_a) {
  const int tid = threadIdx.x;
  // unroll 6 (not 36): cap in-flight NT loads at 6/thread so the scheduler
  // doesn't keep ~144 VGPRs of load results live (spill source).
#pragma unroll 6
  for (int rep = 0; rep < 36; ++rep) {
    int it = tid + rep * 256;                // 9216 float4-loads total
    int row = it / 288, c4 = it % 288;
    int col = c4 << 2;
    const f32x4 v = __builtin_nontemporal_load(
        (const f32x4*)&x1[(size_t)(Mbase + row) * 1152 + col]);
    u16x4 h;
    h.x = f2bf(v.x); h.y = f2bf(v.y); h.z = f2bf(v.z); h.w = f2bf(v.w);
    int dst;
    if (col < 128)      dst = row * 136 + col;
    else if (col < 512) dst = 4352 + row * 392 + (col - 128);
    else                dst = 16896 + row * 648 + (col - 512);
    *(u16x4*)&s_a[dst] = h;
  }
}

template<int PID, int L1, int L2, int L3>
__device__ __forceinline__ void do_path(const float* __restrict__ s_cgw,
                                        const unsigned short* __restrict__ s_a,
                                        const unsigned short* __restrict__ Wt,
                                        const float (&x2v)[9],
                                        int bloc, int kg, int r16, int nbase,
                                        f32x4 (&acc)[2 * L3 + 1][4]) {
  constexpr int D1 = 2 * L1 + 1, D2 = 2 * L2 + 1, D3 = 2 * L3 + 1;
  constexpr int O2 = (L2 == 0) ? 0 : ((L2 == 1) ? 1 : 4);
  constexpr int GB = (L1 == 0) ? 0 : ((L1 == 1) ? 4352 : 16896);
  constexpr int pitch = 128 * D1 + 8;
  // g[i][k] = sum_j x2[o2+j] * cgw[i][j][k]  (per-lane, for this lane's batch row)
  float g[D1][D3];
#pragma unroll
  for (int i = 0; i < D1; ++i)
#pragma unroll
    for (int k = 0; k < D3; ++k) {
      float s = 0.f;
#pragma unroll
      for (int j = 0; j < D2; ++j)
        s += x2v[O2 + j] * s_cgw[PID * 125 + i * 25 + j * 5 + k];
      g[i][k] = s;
    }
  const unsigned short* __restrict__ wbase = Wt + (PID << 14);
  const unsigned short* __restrict__ ap0 = s_a + GB + bloc * pitch;
  // unroll 1: keep per-us transients (av/bw/taw/a0/a1 ~66 regs) from being
  // hoisted across all 4 iterations by the scheduler (the R4/R5 spill source).
#pragma unroll 1
  for (int us = 0; us < 4; ++us) {
    const int u0 = us * 32 + kg * 8;
    // x1 octet: 8 consecutive u, D1 comps each, bf16, from LDS
    const unsigned short* ap = ap0 + u0 * D1;
    u32x4 av[D1];
#pragma unroll
    for (int d = 0; d < D1; ++d) av[d] = *(const u32x4*)(ap + d * 8);
    // weight frags: 8 consecutive u for this lane's w column
    u32x4 bw[4];
#pragma unroll
    for (int nf = 0; nf < 4; ++nf)
      bw[nf] = *(const u32x4*)&wbase[(nbase + nf * 16 + r16) * 128 + u0];
    // t frags (A operand), one per output component k
    unsigned int taw[D3][4];
#pragma unroll
    for (int jp = 0; jp < 4; ++jp) {
      float a0[D1], a1[D1];
#pragma unroll
      for (int i = 0; i < D1; ++i) {
        int e0 = (2 * jp) * D1 + i, e1 = e0 + D1;
        a0[i] = bfw(av[e0 >> 3][(e0 & 7) >> 1], e0 & 1);
        a1[i] = bfw(av[e1 >> 3][(e1 & 7) >> 1], e1 & 1);
      }
#pragma unroll
      for (int k = 0; k < D3; ++k) {
        float t0 = 0.f, t1 = 0.f;
#pragma unroll
        for (int i = 0; i < D1; ++i) { t0 += a0[i] * g[i][k]; t1 += a1[i] * g[i][k]; }
        taw[k][jp] = (unsigned int)f2bf(t0) | ((unsigned int)f2bf(t1) << 16);
      }
    }
#pragma unroll
    for (int k = 0; k < D3; ++k) {
      u32x4 tw;
      tw.x = taw[k][0]; tw.y = taw[k][1]; tw.z = taw[k][2]; tw.w = taw[k][3];
      bf16x8 ta = __builtin_bit_cast(bf16x8, tw);
#pragma unroll
      for (int nf = 0; nf < 4; ++nf)
        acc[k][nf] = __builtin_amdgcn_mfma_f32_16x16x32_bf16(
            ta, __builtin_bit_cast(bf16x8, bw[nf]), acc[k][nf], 0, 0, 0);
    }
  }
}

__global__ void __launch_bounds__(256, 2) fctp_main(
    const float* __restrict__ x1, const float* __restrict__ x2,
    const float* __restrict__ cgw, const unsigned short* __restrict__ Wt,
    float* __restrict__ out) {
  __shared__ float s_cgw[1375];
  __shared__ __align__(16) unsigned short s_a[37632];   // 75264 B x1 tile (bf16)
  const int tid = threadIdx.x;
  const int Mbase = blockIdx.x << 5;

  for (int i = tid; i < 1375; i += 256) s_cgw[i] = cgw[i];
  stage_all(x1, Mbase, s_a);

  const int lane = tid & 63, wid = tid >> 6;
  const int mi = wid >> 1, ni = wid & 1;
  const int r16 = lane & 15, kg = lane >> 4;
  const int bloc = (mi << 4) + r16;   // this lane's batch row within the tile (A side)
  const int nbase = ni << 6;          // this wave's w window

  float x2v[9];
  const float* __restrict__ x2p = x2 + (size_t)(Mbase + bloc) * 9;
#pragma unroll
  for (int j = 0; j < 9; ++j) x2v[j] = x2p[j];

  __syncthreads();                    // the only barrier: x1 tile + cgw ready

  const int bout = Mbase + (mi << 4) + (kg << 2);

  // ---- i3 = 0 (cols [0,128), d3=1): paths 0,4,9 ----
  {
    f32x4 acc[1][4] = {};
    do_path<0, 0, 0, 0>(s_cgw, s_a, Wt, x2v, bloc, kg, r16, nbase, acc);
    do_path<4, 1, 1, 0>(s_cgw, s_a, Wt, x2v, bloc, kg, r16, nbase, acc);
    do_path<9, 2, 2, 0>(s_cgw, s_a, Wt, x2v, bloc, kg, r16, nbase, acc);
#pragma unroll
    for (int nf = 0; nf < 4; ++nf) {
      const int w = nbase + nf * 16 + r16;
#pragma unroll
      for (int r = 0; r < 4; ++r)
        __builtin_nontemporal_store(acc[0][nf][r],
                                    &out[(size_t)(bout + r) * 1152 + w]);
    }
  }
  // ---- i3 = 1 (cols 128 + w*3 + k, d3=3): paths 1,3,6,8 ----
  {
    f32x4 acc[3][4] = {};
    do_path<1, 0, 1, 1>(s_cgw, s_a, Wt, x2v, bloc, kg, r16, nbase, acc);
    do_path<3, 1, 0, 1>(s_cgw, s_a, Wt, x2v, bloc, kg, r16, nbase, acc);
    do_path<6, 1, 2, 1>(s_cgw, s_a, Wt, x2v, bloc, kg, r16, nbase, acc);
    do_path<8, 2, 1, 1>(s_cgw, s_a, Wt, x2v, bloc, kg, r16, nbase, acc);
#pragma unroll
    for (int nf = 0; nf < 4; ++nf) {
      const int w = nbase + nf * 16 + r16;
#pragma unroll
      for (int r = 0; r < 4; ++r) {
        float* o = out + (size_t)(bout + r) * 1152 + 128 + w * 3;
#pragma unroll
        for (int k = 0; k < 3; ++k) o[k] = acc[k][nf][r];
      }
    }
  }
  // ---- i3 = 2 (cols 512 + w*5 + k, d3=5): paths 2,5,7,10 ----
  {
    f32x4 acc[5][4] = {};
    do_path<2, 0, 2, 2>(s_cgw, s_a, Wt, x2v, bloc, kg, r16, nbase, acc);
    do_path<5, 1, 1, 2>(s_cgw, s_a, Wt, x2v, bloc, kg, r16, nbase, acc);
    do_path<7, 2, 0, 2>(s_cgw, s_a, Wt, x2v, bloc, kg, r16, nbase, acc);
    do_path<10, 2, 2, 2>(s_cgw, s_a, Wt, x2v, bloc, kg, r16, nbase, acc);
#pragma unroll
    for (int nf = 0; nf < 4; ++nf) {
      const int w = nbase + nf * 16 + r16;
#pragma unroll
      for (int r = 0; r < 4; ++r) {
        float* o = out + (size_t)(bout + r) * 1152 + 512 + w * 5;
#pragma unroll
        for (int k = 0; k < 5; ++k) o[k] = acc[k][nf][r];
      }
    }
  }
}

extern "C" void kernel_launch(void* const* d_in, const int* in_sizes, int n_in,
                              void* d_out, int out_size, void* d_ws, size_t ws_size,
                              hipStream_t stream) {
  (void)in_sizes; (void)n_in; (void)out_size; (void)ws_size;
  const float* x1 = (const float*)d_in[0];
  const float* x2 = (const float*)d_in[1];
  const float* w  = (const float*)d_in[2];
  float* out = (float*)d_out;
  float* cgw = (float*)d_ws;                                    // 1375 floats
  unsigned short* Wt = (unsigned short*)((char*)d_ws + 8192);   // 11*128*128 bf16
  init_kernel<<<dim3(715), dim3(256), 0, stream>>>(w, Wt, cgw);
  fctp_main<<<dim3(2048), dim3(256), 0, stream>>>(x1, x2, cgw, Wt, out);
}